// Round 1
// baseline (74.807 us; speedup 1.0000x reference)
//
#include <hip/hip_runtime.h>
#include <math.h>

#define TWO_PI 6.283185307179586f

// ---------------------------------------------------------------------------
// K1: A[r][m] (r = b*Cin+i, m = 0..63) = sum_n x[r][n] * cas(2*pi*n*m/8192)
// Grid: (r=64, mblock=2, nhalf=2) = 256 blocks, 256 threads (4 waves).
// Wave w owns modes mblock*32 + w*8 .. +7. Lane l owns float4 n-slices.
// Writes partial sums P[r][m][nhalf] (fp32) to workspace.
// Rotator identity: u = cas(phi), v = cas(-phi);
//   cas(phi + j*D) = cos(jD)*u + sin(jD)*v  (exact), so per float4 element j
//   we keep accA[j] = sum x_j*u, accB[j] = sum x_j*v and combine at the end.
// ---------------------------------------------------------------------------
__global__ __launch_bounds__(256) void k1_dht_big(const float* __restrict__ x,
                                                  float* __restrict__ P) {
  const int r  = blockIdx.x;   // 0..63
  const int mb = blockIdx.y;   // 0..1
  const int nh = blockIdx.z;   // 0..1
  const int t  = threadIdx.x;
  const int l  = t & 63;
  const int w  = t >> 6;
  const int mbase = mb * 32 + w * 8;
  const float* xr = x + r * 8192 + nh * 4096;

  const float step = TWO_PI / 8192.0f;
  float u[8], v[8], Cs[8], Ss[8];
  float accA[8][4];
  float accB[8][3];

#pragma unroll
  for (int q = 0; q < 8; ++q) {
    const int m = mbase + q;
    // initial phase at n = nh*4096 + 4*l, exact mod-8192 reduction
    const int idx0 = ((nh * 4096 + 4 * l) * m) & 8191;
    float s0, c0;
    __sincosf((float)idx0 * step, &s0, &c0);
    u[q] = c0 + s0;   // cas(phi0)
    v[q] = c0 - s0;   // cas(-phi0)
    // per-iteration advance: 256 * m
    const int idxs = (256 * m) & 8191;
    float ss, cs;
    __sincosf((float)idxs * step, &ss, &cs);
    Cs[q] = cs;
    Ss[q] = ss;
#pragma unroll
    for (int j = 0; j < 4; ++j) accA[q][j] = 0.0f;
#pragma unroll
    for (int j = 0; j < 3; ++j) accB[q][j] = 0.0f;
  }

#pragma unroll 4
  for (int it = 0; it < 16; ++it) {
    const float4 xv = *reinterpret_cast<const float4*>(xr + it * 256 + 4 * l);
#pragma unroll
    for (int q = 0; q < 8; ++q) {
      accA[q][0] += xv.x * u[q];
      accA[q][1] += xv.y * u[q];
      accA[q][2] += xv.z * u[q];
      accA[q][3] += xv.w * u[q];
      accB[q][0] += xv.y * v[q];
      accB[q][1] += xv.z * v[q];
      accB[q][2] += xv.w * v[q];
      const float un = Cs[q] * u[q] + Ss[q] * v[q];
      const float vn = Cs[q] * v[q] - Ss[q] * u[q];
      u[q] = un;
      v[q] = vn;
    }
  }

#pragma unroll
  for (int q = 0; q < 8; ++q) {
    const int m = mbase + q;
    const float d = (float)m * step;
    float acc = accA[q][0];  // j=0: cos=1, sin=0
#pragma unroll
    for (int j = 1; j < 4; ++j) {
      float sj, cj;
      __sincosf((float)j * d, &sj, &cj);
      acc += cj * accA[q][j] + sj * accB[q][j - 1];
    }
    // wave (64-lane) butterfly reduction
#pragma unroll
    for (int off = 32; off > 0; off >>= 1) acc += __shfl_xor(acc, off, 64);
    if (l == q) P[(r * 64 + m) * 2 + nh] = acc;
  }
}

// ---------------------------------------------------------------------------
// K2a: small 64-point DHTs.
//   blocks 0..63 : hq[i][o][:] = dht64(w1[i][o][:]) for io = blk*4..+3
//   blocks 64..79: hp[r][:]    = dht64(A[r][:]),  A = P[...,0]+P[...,1]
// ---------------------------------------------------------------------------
__global__ __launch_bounds__(256) void k2a_small_dht(const float* __restrict__ w1,
                                                     const float* __restrict__ P,
                                                     float* __restrict__ hp,
                                                     float* __restrict__ hq) {
  __shared__ float rows[4][64];
  __shared__ float cas64[64];
  const int t = threadIdx.x;
  const int sub = t >> 6;
  const int c = t & 63;
  if (t < 64) {
    float s, cc;
    __sincosf((float)t * (TWO_PI / 64.0f), &s, &cc);
    cas64[t] = cc + s;
  }
  const int b = blockIdx.x;
  if (b < 64) {
    rows[sub][c] = w1[(b * 4 + sub) * 64 + c];
  } else {
    const int r = (b - 64) * 4 + sub;
    rows[sub][c] = P[(r * 64 + c) * 2] + P[(r * 64 + c) * 2 + 1];
  }
  __syncthreads();
  float acc = 0.0f;
#pragma unroll 8
  for (int m = 0; m < 64; ++m) acc += rows[sub][m] * cas64[(m * c) & 63];
  if (b < 64) hq[(b * 4 + sub) * 64 + c] = acc;
  else        hp[((b - 64) * 4 + sub) * 64 + c] = acc;
}

// ---------------------------------------------------------------------------
// K2b: hz[b,o,m] = 0.5*sum_i ((hp+rp)*hq + (hp-rp)*rq); z = dht64(hz)/4096.
// One block per (b,o) = 64 blocks.
// ---------------------------------------------------------------------------
__global__ __launch_bounds__(256) void k2b_mix(const float* __restrict__ hp,
                                               const float* __restrict__ hq,
                                               float* __restrict__ z) {
  const int blk = blockIdx.x;  // 0..63
  const int b = blk >> 4;
  const int o = blk & 15;
  __shared__ float shp[16][64];
  __shared__ float shq[16][64];
  __shared__ float hz[64];
  __shared__ float red[4][64];
  __shared__ float cas64[64];
  const int t = threadIdx.x;
  const int m = t & 63;
  const int sub = t >> 6;
  if (t < 64) {
    float s, cc;
    __sincosf((float)t * (TWO_PI / 64.0f), &s, &cc);
    cas64[t] = cc + s;
  }
  for (int i = sub; i < 16; i += 4) {
    shp[i][m] = hp[(b * 16 + i) * 64 + m];
    shq[i][m] = hq[(i * 16 + o) * 64 + m];
  }
  __syncthreads();
  const int mr = (64 - m) & 63;  // reverse index
  float a = 0.0f;
#pragma unroll
  for (int ii = 0; ii < 4; ++ii) {
    const int i = sub * 4 + ii;
    const float p  = shp[i][m];
    const float pr = shp[i][mr];
    const float qq = shq[i][m];
    const float qr = shq[i][mr];
    a += 0.5f * ((p + pr) * qq + (p - pr) * qr);
  }
  red[sub][m] = a;
  __syncthreads();
  if (t < 64) hz[t] = red[0][t] + red[1][t] + red[2][t] + red[3][t];
  __syncthreads();
  float zz = 0.0f;
#pragma unroll
  for (int j = 0; j < 16; ++j) {
    const int mm = sub * 16 + j;
    zz += hz[mm] * cas64[(mm * m) & 63];
  }
  red[sub][m] = zz;
  __syncthreads();
  if (t < 64)
    z[(b * 16 + o) * 64 + t] =
        (red[0][t] + red[1][t] + red[2][t] + red[3][t]) * (1.0f / 4096.0f);
}

// ---------------------------------------------------------------------------
// K3: out[row][k] = (1/262208) * sum_{m<64} z[row][m] * cas(2*pi*m*k/4097)
// Grid (row=64, kchunk=17), thread per k. Rotator over m (64 steps).
// ---------------------------------------------------------------------------
__global__ __launch_bounds__(256) void k3_out(const float* __restrict__ z,
                                              float* __restrict__ out) {
  const int row = blockIdx.x;  // 0..63
  const int kc  = blockIdx.y;  // 0..16
  __shared__ float zr[64];
  const int t = threadIdx.x;
  if (t < 64) zr[t] = z[row * 64 + t];
  __syncthreads();
  const int k = kc * 256 + t;
  if (k >= 4097) return;
  const float d = (float)k * (TWO_PI / 4097.0f);
  float sd, cd;
  __sincosf(d, &sd, &cd);
  float u = 1.0f, v = 1.0f;  // cas(0), cas(-0)
  float acc = 0.0f;
#pragma unroll 8
  for (int m = 0; m < 64; ++m) {
    acc += zr[m] * u;
    const float un = cd * u + sd * v;
    const float vn = cd * v - sd * u;
    u = un;
    v = vn;
  }
  out[row * 4097 + k] = acc * (1.0f / 262208.0f);
}

// ---------------------------------------------------------------------------
// Workspace layout (floats): P[64*64*2]=8192 | hp[64*64]=4096 |
// hq[16*16*64]=16384 | z[4*16*64]=4096  -> 32768 floats = 128 KiB total.
// ---------------------------------------------------------------------------
extern "C" void kernel_launch(void* const* d_in, const int* in_sizes, int n_in,
                              void* d_out, int out_size, void* d_ws, size_t ws_size,
                              hipStream_t stream) {
  const float* x  = (const float*)d_in[0];   // [4,16,8192]
  const float* w1 = (const float*)d_in[1];   // [16,16,64]
  float* out = (float*)d_out;                // [4,16,4097]
  float* ws = (float*)d_ws;
  float* P  = ws;          // 8192
  float* hp = ws + 8192;   // 4096
  float* hq = ws + 12288;  // 16384
  float* z  = ws + 28672;  // 4096

  k1_dht_big<<<dim3(64, 2, 2), 256, 0, stream>>>(x, P);
  k2a_small_dht<<<80, 256, 0, stream>>>(w1, P, hp, hq);
  k2b_mix<<<64, 256, 0, stream>>>(hp, hq, z);
  k3_out<<<dim3(64, 17), 256, 0, stream>>>(z, out);
}

// Round 2
// 74.605 us; speedup vs baseline: 1.0027x; 1.0027x over previous
//
#include <hip/hip_runtime.h>
#include <math.h>

#define TWO_PI 6.283185307179586f

// ---------------------------------------------------------------------------
// kA: fused big-DHT partials + hq.
//  blocks 0..255 : P[r][m][nh] partial sums of A[r][m] = sum_n x[r][n]*cas(nm)
//                  (r = blk&63, mb = (blk>>6)&1, nh = blk>>7; wave owns 8 modes)
//  blocks 256..319: hq[io][:] = dht64(w1 rows), 4 rows per block.
// ---------------------------------------------------------------------------
__global__ __launch_bounds__(256) void kA(const float* __restrict__ x,
                                          const float* __restrict__ w1,
                                          float* __restrict__ P,
                                          float* __restrict__ hq) {
  __shared__ float rows[4][64];
  __shared__ float cas64[64];
  const int blk = blockIdx.x;
  const int t = threadIdx.x;

  if (blk < 256) {
    const int r  = blk & 63;
    const int mb = (blk >> 6) & 1;
    const int nh = (blk >> 7) & 1;
    const int l  = t & 63;
    const int w  = t >> 6;
    const int mbase = mb * 32 + w * 8;
    const float* xr = x + r * 8192 + nh * 4096;

    const float step = TWO_PI / 8192.0f;
    float u[8], v[8], Cs[8], Ss[8];
    float accA[8][4];
    float accB[8][3];

#pragma unroll
    for (int q = 0; q < 8; ++q) {
      const int m = mbase + q;
      const int idx0 = ((nh * 4096 + 4 * l) * m) & 8191;
      float s0, c0;
      __sincosf((float)idx0 * step, &s0, &c0);
      u[q] = c0 + s0;
      v[q] = c0 - s0;
      const int idxs = (256 * m) & 8191;
      float ss, cs;
      __sincosf((float)idxs * step, &ss, &cs);
      Cs[q] = cs;
      Ss[q] = ss;
#pragma unroll
      for (int j = 0; j < 4; ++j) accA[q][j] = 0.0f;
#pragma unroll
      for (int j = 0; j < 3; ++j) accB[q][j] = 0.0f;
    }

#pragma unroll 8
    for (int it = 0; it < 16; ++it) {
      const float4 xv = *reinterpret_cast<const float4*>(xr + it * 256 + 4 * l);
#pragma unroll
      for (int q = 0; q < 8; ++q) {
        accA[q][0] += xv.x * u[q];
        accA[q][1] += xv.y * u[q];
        accA[q][2] += xv.z * u[q];
        accA[q][3] += xv.w * u[q];
        accB[q][0] += xv.y * v[q];
        accB[q][1] += xv.z * v[q];
        accB[q][2] += xv.w * v[q];
        const float un = Cs[q] * u[q] + Ss[q] * v[q];
        const float vn = Cs[q] * v[q] - Ss[q] * u[q];
        u[q] = un;
        v[q] = vn;
      }
    }

#pragma unroll
    for (int q = 0; q < 8; ++q) {
      const int m = mbase + q;
      const float d = (float)m * step;
      float acc = accA[q][0];
#pragma unroll
      for (int j = 1; j < 4; ++j) {
        float sj, cj;
        __sincosf((float)j * d, &sj, &cj);
        acc += cj * accA[q][j] + sj * accB[q][j - 1];
      }
#pragma unroll
      for (int off = 32; off > 0; off >>= 1) acc += __shfl_xor(acc, off, 64);
      if (l == q) P[(r * 64 + m) * 2 + nh] = acc;
    }
  } else {
    // hq path
    const int sub = t >> 6;
    const int c = t & 63;
    if (t < 64) {
      float s, cc;
      __sincosf((float)t * (TWO_PI / 64.0f), &s, &cc);
      cas64[t] = cc + s;
    }
    const int b2 = blk - 256;  // 0..63
    rows[sub][c] = w1[(b2 * 4 + sub) * 64 + c];
    __syncthreads();
    float acc = 0.0f;
#pragma unroll 8
    for (int m = 0; m < 64; ++m) acc += rows[sub][m] * cas64[(m * c) & 63];
    hq[(b2 * 4 + sub) * 64 + c] = acc;
  }
}

// ---------------------------------------------------------------------------
// kB: one block per (b,o) = 64 blocks. Computes hp rows (from P) in-block,
// then hz mix, then z = dht64(hz)/4096 -> global z.
// ---------------------------------------------------------------------------
__global__ __launch_bounds__(256) void kB(const float* __restrict__ P,
                                          const float* __restrict__ hq,
                                          float* __restrict__ z) {
  const int blk = blockIdx.x;  // 0..63
  const int b = blk >> 4;
  const int o = blk & 15;
  __shared__ float sAT[64][20];  // A transposed: sAT[c][i], padded to 20
  __shared__ float sq[16][64];
  __shared__ float hp[16][64];
  __shared__ float hz[64];
  __shared__ float red[4][64];
  __shared__ float cas64[64];
  const int t = threadIdx.x;
  const int m = t & 63;
  const int sub = t >> 6;

  if (t < 64) {
    float s, cc;
    __sincosf((float)t * (TWO_PI / 64.0f), &s, &cc);
    cas64[t] = cc + s;
  }
  for (int idx = t; idx < 1024; idx += 256) {
    const int i = idx >> 6;
    const int c = idx & 63;
    const float2 pv =
        *reinterpret_cast<const float2*>(&P[(((b * 16 + i) << 6) + c) * 2]);
    sAT[c][i] = pv.x + pv.y;
    sq[i][c] = hq[(((i * 16 + o) << 6)) + c];
  }
  __syncthreads();

  // hp[i][m] for i = sub*4 + j, j=0..3: rotator over c, b128 broadcast reads
  {
    float sd, cd;
    __sincosf((float)m * (TWO_PI / 64.0f), &sd, &cd);
    float u = 1.0f, v = 1.0f;
    float acc0 = 0.0f, acc1 = 0.0f, acc2 = 0.0f, acc3 = 0.0f;
#pragma unroll 8
    for (int c = 0; c < 64; ++c) {
      const float4 av = *reinterpret_cast<const float4*>(&sAT[c][sub * 4]);
      acc0 += av.x * u;
      acc1 += av.y * u;
      acc2 += av.z * u;
      acc3 += av.w * u;
      const float un = cd * u + sd * v;
      const float vn = cd * v - sd * u;
      u = un;
      v = vn;
    }
    hp[sub * 4 + 0][m] = acc0;
    hp[sub * 4 + 1][m] = acc1;
    hp[sub * 4 + 2][m] = acc2;
    hp[sub * 4 + 3][m] = acc3;
  }
  __syncthreads();

  // hz mix partials
  const int mr = (64 - m) & 63;
  float a = 0.0f;
#pragma unroll
  for (int ii = 0; ii < 4; ++ii) {
    const int i = sub * 4 + ii;
    const float p  = hp[i][m];
    const float pr = hp[i][mr];
    const float qq = sq[i][m];
    const float qr = sq[i][mr];
    a += 0.5f * ((p + pr) * qq + (p - pr) * qr);
  }
  red[sub][m] = a;
  __syncthreads();
  if (t < 64) hz[t] = red[0][t] + red[1][t] + red[2][t] + red[3][t];
  __syncthreads();

  // z = dht64(hz) / 4096
  float zz = 0.0f;
#pragma unroll
  for (int jj = 0; jj < 16; ++jj) {
    const int mm = sub * 16 + jj;
    zz += hz[mm] * cas64[(mm * m) & 63];
  }
  red[sub][m] = zz;
  __syncthreads();
  if (t < 64)
    z[blk * 64 + t] =
        (red[0][t] + red[1][t] + red[2][t] + red[3][t]) * (1.0f / 4096.0f);
}

// ---------------------------------------------------------------------------
// kC: out[row][k] = (1/262208) * sum_{m<64} z[row][m] * cas(2*pi*m*k/4097)
// ---------------------------------------------------------------------------
__global__ __launch_bounds__(256) void kC(const float* __restrict__ z,
                                          float* __restrict__ out) {
  const int row = blockIdx.x;  // 0..63
  const int kc  = blockIdx.y;  // 0..16
  __shared__ float zr[64];
  const int t = threadIdx.x;
  if (t < 64) zr[t] = z[row * 64 + t];
  __syncthreads();
  const int k = kc * 256 + t;
  if (k >= 4097) return;
  const float d = (float)k * (TWO_PI / 4097.0f);
  float sd, cd;
  __sincosf(d, &sd, &cd);
  float u = 1.0f, v = 1.0f;
  float acc = 0.0f;
#pragma unroll 8
  for (int m = 0; m < 64; ++m) {
    acc += zr[m] * u;
    const float un = cd * u + sd * v;
    const float vn = cd * v - sd * u;
    u = un;
    v = vn;
  }
  out[row * 4097 + k] = acc * (1.0f / 262208.0f);
}

// ---------------------------------------------------------------------------
// Workspace (floats): P[8192] | hq[16384] | z[4096]
// ---------------------------------------------------------------------------
extern "C" void kernel_launch(void* const* d_in, const int* in_sizes, int n_in,
                              void* d_out, int out_size, void* d_ws, size_t ws_size,
                              hipStream_t stream) {
  const float* x  = (const float*)d_in[0];   // [4,16,8192]
  const float* w1 = (const float*)d_in[1];   // [16,16,64]
  float* out = (float*)d_out;                // [4,16,4097]
  float* ws = (float*)d_ws;
  float* P  = ws;          // 8192
  float* hq = ws + 8192;   // 16384
  float* z  = ws + 24576;  // 4096

  kA<<<320, 256, 0, stream>>>(x, w1, P, hq);
  kB<<<64, 256, 0, stream>>>(P, hq, z);
  kC<<<dim3(64, 17), 256, 0, stream>>>(z, out);
}

// Round 3
// 72.191 us; speedup vs baseline: 1.0362x; 1.0334x over previous
//
#include <hip/hip_runtime.h>
#include <math.h>

#define TWO_PI 6.283185307179586f

// ---------------------------------------------------------------------------
// kA: blocks 0..255: big-DHT partials P[r][m][nh] of
//       A[r][m] = sum_n x[r][n] * cas(2*pi*n*m/8192)
//     (r = blk&63, mb = (blk>>6)&1, nh = blk>>7; wave owns 8 modes, lane owns
//      float4 n-slices).
//     blocks 256..319: hq[io][:] = dht64(w1 rows), 4 rows per block.
// All mod-8192 trig comes from per-block LDS hi/lo tables:
//   angle(idx) = idx*2pi/8192, idx = h*64+g ->
//   sin = sH[h]*cL[g] + cH[h]*sL[g];  cos = cH[h]*cL[g] - sH[h]*sL[g]
// ---------------------------------------------------------------------------
__global__ __launch_bounds__(256) void kA(const float* __restrict__ x,
                                          const float* __restrict__ w1,
                                          float* __restrict__ P,
                                          float* __restrict__ hq) {
  __shared__ float sH[128], cH[128], sL[64], cL[64];
  __shared__ float rows[4][64];
  __shared__ float cas64[64];
  const int blk = blockIdx.x;
  const int t = threadIdx.x;

  if (blk < 256) {
    // ---- build cas-8192 hi/lo tables ----
    if (t < 128) {
      float s, c;
      __sincosf((float)t * (TWO_PI / 128.0f), &s, &c);
      sH[t] = s;
      cH[t] = c;
    } else if (t < 192) {
      const int g = t - 128;
      float s, c;
      __sincosf((float)g * (TWO_PI / 8192.0f), &s, &c);
      sL[g] = s;
      cL[g] = c;
    }
    __syncthreads();

    const int r  = blk & 63;
    const int mb = (blk >> 6) & 1;
    const int nh = (blk >> 7) & 1;
    const int l  = t & 63;
    const int w  = t >> 6;
    const int mbase = mb * 32 + w * 8;
    const float* xr = x + r * 8192 + nh * 4096;

    float u[8], v[8], Cs[8], Ss[8];
    float accA[8][4];
    float accB[8][3];

#pragma unroll
    for (int q = 0; q < 8; ++q) {
      const int m = mbase + q;
      // initial phase at n = nh*4096 + 4*l (exact mod-8192), via tables
      const int idx0 = ((nh * 4096 + 4 * l) * m) & 8191;
      const int h = idx0 >> 6, g = idx0 & 63;
      const float c0 = cH[h] * cL[g] - sH[h] * sL[g];
      const float s0 = sH[h] * cL[g] + cH[h] * sL[g];
      u[q] = c0 + s0;
      v[q] = c0 - s0;
      // per-iteration advance angle: (256*m mod 8192)*step = hi-table[(4m)&127]
      const int ih = (4 * m) & 127;
      Cs[q] = cH[ih];
      Ss[q] = sH[ih];
#pragma unroll
      for (int j = 0; j < 4; ++j) accA[q][j] = 0.0f;
#pragma unroll
      for (int j = 0; j < 3; ++j) accB[q][j] = 0.0f;
    }

#pragma unroll 8
    for (int it = 0; it < 16; ++it) {
      const float4 xv = *reinterpret_cast<const float4*>(xr + it * 256 + 4 * l);
#pragma unroll
      for (int q = 0; q < 8; ++q) {
        accA[q][0] += xv.x * u[q];
        accA[q][1] += xv.y * u[q];
        accA[q][2] += xv.z * u[q];
        accA[q][3] += xv.w * u[q];
        accB[q][0] += xv.y * v[q];
        accB[q][1] += xv.z * v[q];
        accB[q][2] += xv.w * v[q];
        const float un = Cs[q] * u[q] + Ss[q] * v[q];
        const float vn = Cs[q] * v[q] - Ss[q] * u[q];
        u[q] = un;
        v[q] = vn;
      }
    }

    // combine weights cos(j*m*step), sin(j*m*step) for (q, j=1..3):
    // lane (q*4+j) computes them from the tables, everyone shfl-reads.
    float cval, sval;
    {
      const int qq = (l >> 2) & 7;
      const int jj = l & 3;
      const int jm = jj * (mbase + qq);  // <= 3*63, fits low table range
      const int h = jm >> 6, g = jm & 63;
      cval = cH[h] * cL[g] - sH[h] * sL[g];
      sval = sH[h] * cL[g] + cH[h] * sL[g];
    }

#pragma unroll
    for (int q = 0; q < 8; ++q) {
      float acc = accA[q][0];
#pragma unroll
      for (int j = 1; j < 4; ++j) {
        const float cj = __shfl(cval, q * 4 + j, 64);
        const float sj = __shfl(sval, q * 4 + j, 64);
        acc += cj * accA[q][j] + sj * accB[q][j - 1];
      }
#pragma unroll
      for (int off = 32; off > 0; off >>= 1) acc += __shfl_xor(acc, off, 64);
      if (l == q) P[(r * 64 + (mbase + q)) * 2 + nh] = acc;
    }
  } else {
    // ---- hq path ----
    const int sub = t >> 6;
    const int c = t & 63;
    if (t < 64) {
      float s, cc;
      __sincosf((float)t * (TWO_PI / 64.0f), &s, &cc);
      cas64[t] = cc + s;
    }
    const int b2 = blk - 256;  // 0..63
    rows[sub][c] = w1[(b2 * 4 + sub) * 64 + c];
    __syncthreads();
    float acc = 0.0f;
#pragma unroll 8
    for (int m = 0; m < 64; ++m) acc += rows[sub][m] * cas64[(m * c) & 63];
    hq[(b2 * 4 + sub) * 64 + c] = acc;
  }
}

// ---------------------------------------------------------------------------
// kB: one block per (b,o) = 64 blocks. hp rows from P in-block, hz mix,
// z = dht64(hz)/4096.
// ---------------------------------------------------------------------------
__global__ __launch_bounds__(256) void kB(const float* __restrict__ P,
                                          const float* __restrict__ hq,
                                          float* __restrict__ z) {
  const int blk = blockIdx.x;  // 0..63
  const int b = blk >> 4;
  const int o = blk & 15;
  __shared__ float sAT[64][20];  // A transposed, padded
  __shared__ float sq[16][64];
  __shared__ float hp[16][64];
  __shared__ float hz[64];
  __shared__ float red[4][64];
  __shared__ float cas64[64];
  const int t = threadIdx.x;
  const int m = t & 63;
  const int sub = t >> 6;

  if (t < 64) {
    float s, cc;
    __sincosf((float)t * (TWO_PI / 64.0f), &s, &cc);
    cas64[t] = cc + s;
  }
  for (int idx = t; idx < 1024; idx += 256) {
    const int i = idx >> 6;
    const int c = idx & 63;
    const float2 pv =
        *reinterpret_cast<const float2*>(&P[(((b * 16 + i) << 6) + c) * 2]);
    sAT[c][i] = pv.x + pv.y;
    sq[i][c] = hq[(((i * 16 + o) << 6)) + c];
  }
  __syncthreads();

  {
    float sd, cd;
    __sincosf((float)m * (TWO_PI / 64.0f), &sd, &cd);
    float u = 1.0f, v = 1.0f;
    float acc0 = 0.0f, acc1 = 0.0f, acc2 = 0.0f, acc3 = 0.0f;
#pragma unroll 8
    for (int c = 0; c < 64; ++c) {
      const float4 av = *reinterpret_cast<const float4*>(&sAT[c][sub * 4]);
      acc0 += av.x * u;
      acc1 += av.y * u;
      acc2 += av.z * u;
      acc3 += av.w * u;
      const float un = cd * u + sd * v;
      const float vn = cd * v - sd * u;
      u = un;
      v = vn;
    }
    hp[sub * 4 + 0][m] = acc0;
    hp[sub * 4 + 1][m] = acc1;
    hp[sub * 4 + 2][m] = acc2;
    hp[sub * 4 + 3][m] = acc3;
  }
  __syncthreads();

  const int mr = (64 - m) & 63;
  float a = 0.0f;
#pragma unroll
  for (int ii = 0; ii < 4; ++ii) {
    const int i = sub * 4 + ii;
    const float p  = hp[i][m];
    const float pr = hp[i][mr];
    const float qq = sq[i][m];
    const float qr = sq[i][mr];
    a += 0.5f * ((p + pr) * qq + (p - pr) * qr);
  }
  red[sub][m] = a;
  __syncthreads();
  if (t < 64) hz[t] = red[0][t] + red[1][t] + red[2][t] + red[3][t];
  __syncthreads();

  float zz = 0.0f;
#pragma unroll
  for (int jj = 0; jj < 16; ++jj) {
    const int mm = sub * 16 + jj;
    zz += hz[mm] * cas64[(mm * m) & 63];
  }
  red[sub][m] = zz;
  __syncthreads();
  if (t < 64)
    z[blk * 64 + t] =
        (red[0][t] + red[1][t] + red[2][t] + red[3][t]) * (1.0f / 4096.0f);
}

// ---------------------------------------------------------------------------
// kC: out[row][k] = (1/262208) * sum_{m<64} z[row][m] * cas(2*pi*m*k/4097)
// m = 8a+b split: cas(m*th) = cos(b*th)*cas(8a*th) + sin(b*th)*cas(-8a*th)
//   A[b] = sum_a z[8a+b]*u_a, B[b] = sum_a z[8a+b]*v_a,
//   u_a = cas(8a*th), v_a = cas(-8a*th) rotated by 8*th per a-step.
//   out = sum_b cw[b]*A[b] + sw[b]*B[b].
// ---------------------------------------------------------------------------
__global__ __launch_bounds__(256) void kC(const float* __restrict__ z,
                                          float* __restrict__ out) {
  const int row = blockIdx.x;  // 0..63
  const int kc  = blockIdx.y;  // 0..16
  __shared__ float zr[64];
  const int t = threadIdx.x;
  if (t < 64) zr[t] = z[row * 64 + t];
  __syncthreads();
  const int k = kc * 256 + t;
  if (k >= 4097) return;
  const float th = (float)k * (TWO_PI / 4097.0f);
  float s1, c1;
  __sincosf(th, &s1, &c1);

  float cw[8], sw[8];
  cw[0] = 1.0f; sw[0] = 0.0f;
  cw[1] = c1;   sw[1] = s1;
#pragma unroll
  for (int b = 2; b < 8; ++b) {
    cw[b] = cw[b - 1] * c1 - sw[b - 1] * s1;
    sw[b] = sw[b - 1] * c1 + cw[b - 1] * s1;
  }
  const float c8 = cw[7] * c1 - sw[7] * s1;
  const float s8 = sw[7] * c1 + cw[7] * s1;

  float A[8], B[8];
#pragma unroll
  for (int b = 0; b < 8; ++b) { A[b] = 0.0f; B[b] = 0.0f; }
  float u = 1.0f, v = 1.0f;
#pragma unroll
  for (int a = 0; a < 8; ++a) {
#pragma unroll
    for (int b = 0; b < 8; ++b) {
      const float zz = zr[a * 8 + b];
      A[b] += zz * u;
      B[b] += zz * v;
    }
    const float un = c8 * u + s8 * v;
    const float vn = c8 * v - s8 * u;
    u = un;
    v = vn;
  }
  float acc = 0.0f;
#pragma unroll
  for (int b = 0; b < 8; ++b) acc += cw[b] * A[b] + sw[b] * B[b];
  out[row * 4097 + k] = acc * (1.0f / 262208.0f);
}

// ---------------------------------------------------------------------------
// Workspace (floats): P[8192] | hq[16384] | z[4096]
// ---------------------------------------------------------------------------
extern "C" void kernel_launch(void* const* d_in, const int* in_sizes, int n_in,
                              void* d_out, int out_size, void* d_ws, size_t ws_size,
                              hipStream_t stream) {
  const float* x  = (const float*)d_in[0];   // [4,16,8192]
  const float* w1 = (const float*)d_in[1];   // [16,16,64]
  float* out = (float*)d_out;                // [4,16,4097]
  float* ws = (float*)d_ws;
  float* P  = ws;          // 8192
  float* hq = ws + 8192;   // 16384
  float* z  = ws + 24576;  // 4096

  kA<<<320, 256, 0, stream>>>(x, w1, P, hq);
  kB<<<64, 256, 0, stream>>>(P, hq, z);
  kC<<<dim3(64, 17), 256, 0, stream>>>(z, out);
}

// Round 4
// 70.361 us; speedup vs baseline: 1.0632x; 1.0260x over previous
//
#include <hip/hip_runtime.h>
#include <math.h>

#define TWO_PI 6.283185307179586f

// ---------------------------------------------------------------------------
// kA: big-DHT partials P[r][m][nh] of A[r][m] = sum_n x[r][n]*cas(2pi n m/8192)
// Grid: exactly 256 blocks (r = blk&63, mb = (blk>>6)&1, nh = blk>>7) = 1/CU.
// Wave owns 8 modes; lane owns float4 n-slices. All trig from LDS hi/lo tables.
// ---------------------------------------------------------------------------
__global__ __launch_bounds__(256) void kA(const float* __restrict__ x,
                                          float* __restrict__ P) {
  __shared__ float sH[128], cH[128], sL[64], cL[64];
  const int blk = blockIdx.x;
  const int t = threadIdx.x;

  if (t < 128) {
    float s, c;
    __sincosf((float)t * (TWO_PI / 128.0f), &s, &c);
    sH[t] = s;
    cH[t] = c;
  } else if (t < 192) {
    const int g = t - 128;
    float s, c;
    __sincosf((float)g * (TWO_PI / 8192.0f), &s, &c);
    sL[g] = s;
    cL[g] = c;
  }
  __syncthreads();

  const int r  = blk & 63;
  const int mb = (blk >> 6) & 1;
  const int nh = (blk >> 7) & 1;
  const int l  = t & 63;
  const int w  = t >> 6;
  const int mbase = mb * 32 + w * 8;
  const float* xr = x + r * 8192 + nh * 4096;

  float u[8], v[8], Cs[8], Ss[8];
  float accA[8][4];
  float accB[8][3];

#pragma unroll
  for (int q = 0; q < 8; ++q) {
    const int m = mbase + q;
    const int idx0 = ((nh * 4096 + 4 * l) * m) & 8191;
    const int h = idx0 >> 6, g = idx0 & 63;
    const float c0 = cH[h] * cL[g] - sH[h] * sL[g];
    const float s0 = sH[h] * cL[g] + cH[h] * sL[g];
    u[q] = c0 + s0;
    v[q] = c0 - s0;
    const int ih = (4 * m) & 127;  // 256*m mod 8192 lands on the hi table
    Cs[q] = cH[ih];
    Ss[q] = sH[ih];
#pragma unroll
    for (int j = 0; j < 4; ++j) accA[q][j] = 0.0f;
#pragma unroll
    for (int j = 0; j < 3; ++j) accB[q][j] = 0.0f;
  }

#pragma unroll 8
  for (int it = 0; it < 16; ++it) {
    const float4 xv = *reinterpret_cast<const float4*>(xr + it * 256 + 4 * l);
#pragma unroll
    for (int q = 0; q < 8; ++q) {
      accA[q][0] += xv.x * u[q];
      accA[q][1] += xv.y * u[q];
      accA[q][2] += xv.z * u[q];
      accA[q][3] += xv.w * u[q];
      accB[q][0] += xv.y * v[q];
      accB[q][1] += xv.z * v[q];
      accB[q][2] += xv.w * v[q];
      const float un = Cs[q] * u[q] + Ss[q] * v[q];
      const float vn = Cs[q] * v[q] - Ss[q] * u[q];
      u[q] = un;
      v[q] = vn;
    }
  }

  // combine weights cos(j*m*step), sin(j*m*step): lane (q*4+j) computes, shfl.
  float cval, sval;
  {
    const int qq = (l >> 2) & 7;
    const int jj = l & 3;
    const int jm = jj * (mbase + qq);  // <= 189 < 8192
    const int h = jm >> 6, g = jm & 63;
    cval = cH[h] * cL[g] - sH[h] * sL[g];
    sval = sH[h] * cL[g] + cH[h] * sL[g];
  }

#pragma unroll
  for (int q = 0; q < 8; ++q) {
    float acc = accA[q][0];
#pragma unroll
    for (int j = 1; j < 4; ++j) {
      const float cj = __shfl(cval, q * 4 + j, 64);
      const float sj = __shfl(sval, q * 4 + j, 64);
      acc += cj * accA[q][j] + sj * accB[q][j - 1];
    }
#pragma unroll
    for (int off = 32; off > 0; off >>= 1) acc += __shfl_xor(acc, off, 64);
    if (l == q) P[(r * 64 + (mbase + q)) * 2 + nh] = acc;
  }
}

// ---------------------------------------------------------------------------
// kB: DHT convolution theorem collapses hp/hq/hz/dht64(hz):
//   z[b,o,m] = (1/64) * sum_i sum_j A[b,i,j] * w1[i,o,(m-j)&63]
// Grid: 256 blocks = (b,o,mq); block computes m = mq*16..+15.
// Threads: wave w owns i = 4w..4w+3; lane = jq*16 + ml handles j-quarter jq,
// output m = mq*16+ml. Both LDS read patterns are <=2-way bank aliased (free).
// ---------------------------------------------------------------------------
__global__ __launch_bounds__(256) void kB(const float* __restrict__ P,
                                          const float* __restrict__ w1,
                                          float* __restrict__ z) {
  const int blk = blockIdx.x;        // 0..255
  const int b  = blk >> 6;           // 0..3
  const int o  = (blk >> 2) & 15;    // 0..15
  const int mq = blk & 3;            // 0..3
  __shared__ float sA[16][64];
  __shared__ float sW[16][64];
  __shared__ float red[4][16];
  const int t = threadIdx.x;

  for (int idx = t; idx < 1024; idx += 256) {
    const int i = idx >> 6;
    const int c = idx & 63;
    const float2 pv =
        *reinterpret_cast<const float2*>(&P[(((b * 16 + i) << 6) + c) * 2]);
    sA[i][c] = pv.x + pv.y;
    sW[i][c] = w1[((i * 16 + o) << 6) + c];
  }
  __syncthreads();

  const int w  = t >> 6;        // i-group
  const int l  = t & 63;
  const int jq = l >> 4;        // j-quarter
  const int ml = l & 15;        // local m
  const int m  = mq * 16 + ml;

  float acc = 0.0f;
#pragma unroll
  for (int ii = 0; ii < 4; ++ii) {
    const int i = w * 4 + ii;
#pragma unroll
    for (int jb = 0; jb < 4; ++jb) {
      const float4 a4 =
          *reinterpret_cast<const float4*>(&sA[i][jq * 16 + jb * 4]);
      const int j0 = jq * 16 + jb * 4;
      acc += a4.x * sW[i][(m - j0) & 63];
      acc += a4.y * sW[i][(m - j0 - 1) & 63];
      acc += a4.z * sW[i][(m - j0 - 2) & 63];
      acc += a4.w * sW[i][(m - j0 - 3) & 63];
    }
  }
  // reduce over jq within the wave (lane xor 16, 32 flips jq bits)
  acc += __shfl_xor(acc, 16, 64);
  acc += __shfl_xor(acc, 32, 64);
  if (jq == 0) red[w][ml] = acc;
  __syncthreads();
  if (t < 16)
    z[(((b * 16 + o) << 6)) + m] =
        (red[0][t] + red[1][t] + red[2][t] + red[3][t]) * (1.0f / 64.0f);
}

// ---------------------------------------------------------------------------
// kC: out[row][k] = (1/262208) * sum_{m<64} z[row][m] * cas(2*pi*m*k/4097)
// m = 8a+b split: one sincos per thread, incremental weights, 8-step rotator.
// ---------------------------------------------------------------------------
__global__ __launch_bounds__(256) void kC(const float* __restrict__ z,
                                          float* __restrict__ out) {
  const int row = blockIdx.x;  // 0..63
  const int kc  = blockIdx.y;  // 0..16
  __shared__ float zr[64];
  const int t = threadIdx.x;
  if (t < 64) zr[t] = z[row * 64 + t];
  __syncthreads();
  const int k = kc * 256 + t;
  if (k >= 4097) return;
  const float th = (float)k * (TWO_PI / 4097.0f);
  float s1, c1;
  __sincosf(th, &s1, &c1);

  float cw[8], sw[8];
  cw[0] = 1.0f; sw[0] = 0.0f;
  cw[1] = c1;   sw[1] = s1;
#pragma unroll
  for (int b = 2; b < 8; ++b) {
    cw[b] = cw[b - 1] * c1 - sw[b - 1] * s1;
    sw[b] = sw[b - 1] * c1 + cw[b - 1] * s1;
  }
  const float c8 = cw[7] * c1 - sw[7] * s1;
  const float s8 = sw[7] * c1 + cw[7] * s1;

  float A[8], B[8];
#pragma unroll
  for (int b = 0; b < 8; ++b) { A[b] = 0.0f; B[b] = 0.0f; }
  float u = 1.0f, v = 1.0f;
#pragma unroll
  for (int a = 0; a < 8; ++a) {
#pragma unroll
    for (int b = 0; b < 8; ++b) {
      const float zz = zr[a * 8 + b];
      A[b] += zz * u;
      B[b] += zz * v;
    }
    const float un = c8 * u + s8 * v;
    const float vn = c8 * v - s8 * u;
    u = un;
    v = vn;
  }
  float acc = 0.0f;
#pragma unroll
  for (int b = 0; b < 8; ++b) acc += cw[b] * A[b] + sw[b] * B[b];
  out[row * 4097 + k] = acc * (1.0f / 262208.0f);
}

// ---------------------------------------------------------------------------
// Workspace (floats): P[8192] | z[4096]
// ---------------------------------------------------------------------------
extern "C" void kernel_launch(void* const* d_in, const int* in_sizes, int n_in,
                              void* d_out, int out_size, void* d_ws, size_t ws_size,
                              hipStream_t stream) {
  const float* x  = (const float*)d_in[0];   // [4,16,8192]
  const float* w1 = (const float*)d_in[1];   // [16,16,64]
  float* out = (float*)d_out;                // [4,16,4097]
  float* ws = (float*)d_ws;
  float* P  = ws;         // 8192
  float* z  = ws + 8192;  // 4096

  kA<<<256, 256, 0, stream>>>(x, P);
  kB<<<256, 256, 0, stream>>>(P, w1, z);
  kC<<<dim3(64, 17), 256, 0, stream>>>(z, out);
}